// Round 15
// baseline (1115.029 us; speedup 1.0000x reference)
//
#include <hip/hip_runtime.h>

#define SWEEPS 6
#define HSTRIDE 4112   // hTbuf row stride: 4096 + front pad(1) + slack, %4==0
#define WROW 140       // skewed W image row: pc(rl) = rl + 4*(rl>>5), max 139
#define WTSZ (8 * 256 * WROW)   // one W image: 8 rtiles x 256 k x 140

__device__ __forceinline__ float sig_(float x) { return 1.0f / (1.0f + __expf(-x)); }
__device__ __forceinline__ float th_(float x)  { return 1.0f - 2.0f / (__expf(2.0f * x) + 1.0f); }

// async global->LDS, 16B per lane. LDS dest rule: wave-uniform base + lane*16.
__device__ __forceinline__ void gload_lds16(const float* g, float* l) {
    __builtin_amdgcn_global_load_lds(
        (const __attribute__((address_space(1))) unsigned*)g,
        (__attribute__((address_space(3))) unsigned*)l, 16, 0, 0);
}

// ---------------------------------------------------------------------------
// W image builder: WT[rt][k][pc(rl)] = W[rowmap(rt,rl)][k], rowmap linear
// (ilv=0) or LSTM gate-interleaved rl=ii*4+gi (ilv=1). Runs once per matrix.
// ---------------------------------------------------------------------------
__global__ __launch_bounds__(256)
void wtrans(const float* __restrict__ W, float* __restrict__ WT, int ilv)
{
    __shared__ float s[32 * WROW];
    const int tid = threadIdx.x;
    const int k0 = blockIdx.x * 32;
    const int rt = blockIdx.y;
    #pragma unroll
    for (int p = 0; p < 4; ++p) {
        int idx = tid + p * 256;
        int rl = idx >> 3, k4 = idx & 7;
        int row = ilv ? ((rl & 3) * 256 + rt * 32 + (rl >> 2))
                      : (rt * 128 + rl);
        float4 v = *(const float4*)&W[row * 256 + k0 + k4 * 4];
        int pc = rl + ((rl >> 5) << 2);
        s[(k4 * 4 + 0) * WROW + pc] = v.x;
        s[(k4 * 4 + 1) * WROW + pc] = v.y;
        s[(k4 * 4 + 2) * WROW + pc] = v.z;
        s[(k4 * 4 + 3) * WROW + pc] = v.w;
    }
    __syncthreads();
    float* dst = WT + (size_t)(rt * 256 + k0) * WROW;
    for (int i = tid; i < 32 * WROW; i += 256) dst[i] = s[i];
}

// ---------------------------------------------------------------------------
// emb2 build: emb2[v][j] = sum_k emb[v][k]*tWih[j][k] + tb[j]   (j = 0..1023)
// grid (32, 16), block 256, tile 64v x 64j, 4x4 microtile. 512 blocks.
// ---------------------------------------------------------------------------
__global__ __launch_bounds__(256, 2)
void gemm_emb2(const float* __restrict__ A, const float* __restrict__ Wt,
               const float* __restrict__ bias, float* __restrict__ Cout, int M)
{
    __shared__ float a_lds[32][68];
    __shared__ float b_lds[32][68];
    const int tid = threadIdx.x;
    const int tn = tid & 15;
    const int th = tid >> 4;
    const int m0 = blockIdx.x * 64;
    const int j0 = blockIdx.y * 64;

    float acc[4][4];
    #pragma unroll
    for (int x = 0; x < 4; ++x)
        #pragma unroll
        for (int y = 0; y < 4; ++y) acc[x][y] = 0.f;

    float4 abuf[2], bbuf[2];
    auto load_t = [&](int k0) {
        #pragma unroll
        for (int p = 0; p < 2; ++p) {
            int idx = tid + p * 256, ml = idx >> 3, k4 = idx & 7;
            int row = m0 + ml;
            abuf[p] = (row < M) ? *(const float4*)&A[row * 256 + k0 + k4 * 4]
                                : make_float4(0.f, 0.f, 0.f, 0.f);
            bbuf[p] = *(const float4*)&Wt[(j0 + ml) * 256 + k0 + k4 * 4];
        }
    };
    auto store_t = [&]() {
        #pragma unroll
        for (int p = 0; p < 2; ++p) {
            int idx = tid + p * 256, ml = idx >> 3, k4 = idx & 7;
            a_lds[k4 * 4 + 0][ml] = abuf[p].x;
            a_lds[k4 * 4 + 1][ml] = abuf[p].y;
            a_lds[k4 * 4 + 2][ml] = abuf[p].z;
            a_lds[k4 * 4 + 3][ml] = abuf[p].w;
            b_lds[k4 * 4 + 0][ml] = bbuf[p].x;
            b_lds[k4 * 4 + 1][ml] = bbuf[p].y;
            b_lds[k4 * 4 + 2][ml] = bbuf[p].z;
            b_lds[k4 * 4 + 3][ml] = bbuf[p].w;
        }
    };

    load_t(0); store_t(); __syncthreads();
    for (int c = 0; c < 8; ++c) {
        if (c < 7) load_t((c + 1) * 32);
        #pragma unroll 8
        for (int k = 0; k < 32; ++k) {
            float4 a4 = *(const float4*)&a_lds[k][tn * 4];
            float4 b4 = *(const float4*)&b_lds[k][th * 4];
            float av[4] = {a4.x, a4.y, a4.z, a4.w};
            float bv[4] = {b4.x, b4.y, b4.z, b4.w};
            #pragma unroll
            for (int mi = 0; mi < 4; ++mi)
                #pragma unroll
                for (int ji = 0; ji < 4; ++ji)
                    acc[mi][ji] += av[mi] * bv[ji];
        }
        __syncthreads();
        if (c < 7) { store_t(); __syncthreads(); }
    }

    const int jcol = j0 + th * 4;
    float4 bs = *(const float4*)&bias[jcol];
    #pragma unroll
    for (int mi = 0; mi < 4; ++mi) {
        int row = m0 + tn * 4 + mi;
        if (row < M) {
            float4 o;
            o.x = acc[mi][0] + bs.x;
            o.y = acc[mi][1] + bs.y;
            o.z = acc[mi][2] + bs.z;
            o.w = acc[mi][3] + bs.w;
            *(float4*)&Cout[row * 1024 + jcol] = o;
        }
    }
}

// ---------------------------------------------------------------------------
// Counting sort of sequences by length, DESCENDING. One block.
// ---------------------------------------------------------------------------
__global__ __launch_bounds__(256)
void sortlen(const int* __restrict__ len, int* __restrict__ perm,
             int* __restrict__ actcnt)
{
    __shared__ int cnt[17], off[17];
    const int tid = threadIdx.x;
    if (tid < 17) cnt[tid] = 0;
    __syncthreads();
    for (int n = tid; n < 4096; n += 256) atomicAdd(&cnt[len[n]], 1);
    __syncthreads();
    if (tid == 0) {
        int run = 0;
        for (int L = 16; L >= 1; --L) { off[L] = run; run += cnt[L]; }
        actcnt[16] = 0;
        for (int t = 1; t < 16; ++t) actcnt[t] = off[t];
        actcnt[0] = 4096;
    }
    __syncthreads();
    for (int n = tid; n < 4096; n += 256) {
        int pos = atomicAdd(&off[len[n]], 1);
        perm[pos] = n;
    }
}

// ---------------------------------------------------------------------------
// Token-LSTM step 0 (h0=c0=0 -> pointwise emb2 gather), TRANSPOSED + sorted.
// ---------------------------------------------------------------------------
__global__ __launch_bounds__(256)
void step0T(const int* __restrict__ tok, const int* __restrict__ perm,
            const int* __restrict__ actcnt, const float* __restrict__ emb2,
            float* __restrict__ cT, float* __restrict__ hT0,
            float* __restrict__ featsT)
{
    const int tid = threadIdx.x;
    const int tn = tid & 15, tu = tid >> 4;
    const int u  = blockIdx.y * 16 + tu;
    const int n0 = blockIdx.x * 64 + tn * 4;
    const int a1 = actcnt[1];
    int4 pn = *(const int4*)&perm[n0];
    const int pns[4] = {pn.x, pn.y, pn.z, pn.w};
    float h4[4], c4[4];
    #pragma unroll
    for (int j = 0; j < 4; ++j) {
        int v = tok[pns[j] * 16];
        const float* e = emb2 + v * 1024 + u;
        float ig = e[0], gg = e[512], og = e[768];
        float c = sig_(ig) * th_(gg);
        float h = sig_(og) * th_(c);
        c4[j] = c; h4[j] = h;
        if (n0 + j >= a1) featsT[u * 4096 + pns[j]] = h;   // len == 1
    }
    *(float4*)&cT[u * 4096 + n0]  = make_float4(c4[0], c4[1], c4[2], c4[3]);
    *(float4*)&hT0[u * 4096 + n0] = make_float4(h4[0], h4[1], h4[2], h4[3]);
}

// ---------------------------------------------------------------------------
// Token-LSTM step t (t>=1), fused, TRANSPOSED, sorted, 128r x 128s, 8x8.
// grid (32, 8), block 256. Lane map tr=tid&15 (r-octet), ts=tid>>4 (s-octet):
// per-wave ts spans 4 values -> h-reads are 4 distinct b128 at disjoint bank
// quads = CONFLICT-FREE; w-reads on the skewed image = 2-way (free).
// All staging async global_load_lds (zero LDS writes). K-chunks of 16,
// double-buffered, one barrier per chunk (16 chunks). LDS 34.3 KB.
// ---------------------------------------------------------------------------
__global__ __launch_bounds__(256, 1)
void stepT(const float* __restrict__ WT, const float* __restrict__ hTprev,
           const int* __restrict__ tok, int t, const float* __restrict__ emb2,
           const int* __restrict__ perm, const int* __restrict__ actcnt,
           float* __restrict__ cT, float* __restrict__ hTnext,
           float* __restrict__ featsT)
{
    const int s0 = blockIdx.x * 128;
    const int a_t  = actcnt[t];
    if (s0 >= a_t) return;                // inactive tile: all lengths <= t
    const int a_t1 = actcnt[t + 1];

    __shared__ float w_lds[2][16 * WROW]; // 16k x 140 skewed image chunk
    __shared__ float h_lds[2][16][128];   // 16k x 128s, linear (async dest)
    const int tid = threadIdx.x;
    const int tr = tid & 15;              // r-octet
    const int ts = tid >> 4;              // s-octet
    const int ub = blockIdx.y;            // unit-tile (32 units)
    const int scol = s0 + ts * 8;
    const int wphys = tr * 8 + ((tr >> 2) << 2);

    // prefetch epilogue inputs early (independent of GEMM)
    int4 pn0 = *(const int4*)&perm[scol];
    int4 pn1 = *(const int4*)&perm[scol + 4];
    const int pns[8] = {pn0.x, pn0.y, pn0.z, pn0.w, pn1.x, pn1.y, pn1.z, pn1.w};
    int vids[8];
    #pragma unroll
    for (int j = 0; j < 8; ++j) vids[j] = tok[pns[j] * 16 + t];

    float acc[8][8];
    #pragma unroll
    for (int x = 0; x < 8; ++x)
        #pragma unroll
        for (int y = 0; y < 8; ++y) acc[x][y] = 0.f;

    auto issue_w = [&](int c, int b) {    // 16*140/4 = 560 16B units
        const float* src = WT + (size_t)(ub * 256 + c * 16) * WROW;
        #pragma unroll
        for (int p = 0; p < 2; ++p) {
            int idx = tid + p * 256;
            gload_lds16(src + idx * 4, &w_lds[b][idx * 4]);
        }
        if (tid < 48) {
            int idx = 512 + tid;
            gload_lds16(src + idx * 4, &w_lds[b][idx * 4]);
        }
    };
    auto issue_h = [&](int k0, int b) {   // 16 rows x 32 units = 512 units
        #pragma unroll
        for (int p = 0; p < 2; ++p) {
            int idx = tid + p * 256;
            int jj = idx >> 5, s4 = idx & 31;
            gload_lds16(&hTprev[(k0 + jj) * 4096 + s0 + s4 * 4],
                        &h_lds[b][jj][s4 * 4]);
        }
    };

    issue_w(0, 0); issue_h(0, 0); __syncthreads();
    for (int c = 0; c < 16; ++c) {
        const int b = c & 1;
        if (c < 15) { issue_w(c + 1, b ^ 1); issue_h((c + 1) * 16, b ^ 1); }
        #pragma unroll
        for (int k = 0; k < 16; ++k) {
            float4 w0 = *(const float4*)&w_lds[b][k * WROW + wphys];
            float4 w1 = *(const float4*)&w_lds[b][k * WROW + wphys + 4];
            float4 h0 = *(const float4*)&h_lds[b][k][ts * 8];
            float4 h1 = *(const float4*)&h_lds[b][k][ts * 8 + 4];
            float wa[8] = {w0.x, w0.y, w0.z, w0.w, w1.x, w1.y, w1.z, w1.w};
            float ha[8] = {h0.x, h0.y, h0.z, h0.w, h1.x, h1.y, h1.z, h1.w};
            #pragma unroll
            for (int ri = 0; ri < 8; ++ri)
                #pragma unroll
                for (int si = 0; si < 8; ++si)
                    acc[ri][si] += wa[ri] * ha[si];
        }
        __syncthreads();                  // drains async loads + barrier
    }

    // epilogue: 2 units x 8 slots (acc row = half*4 + gate)
    #pragma unroll
    for (int half = 0; half < 2; ++half) {
        const int u = ub * 32 + tr * 2 + half;
        float4 ca = *(const float4*)&cT[u * 4096 + scol];
        float4 cb = *(const float4*)&cT[u * 4096 + scol + 4];
        float cold[8] = {ca.x, ca.y, ca.z, ca.w, cb.x, cb.y, cb.z, cb.w};
        float c8[8], h8[8];
        #pragma unroll
        for (int j = 0; j < 8; ++j) {
            const float* e = emb2 + vids[j] * 1024 + u;
            float ig = acc[half * 4 + 0][j] + e[0];
            float fg = acc[half * 4 + 1][j] + e[256];
            float gg = acc[half * 4 + 2][j] + e[512];
            float og = acc[half * 4 + 3][j] + e[768];
            float cc = sig_(fg) * cold[j] + sig_(ig) * th_(gg);
            c8[j] = cc;
            h8[j] = sig_(og) * th_(cc);
            int p = scol + j;
            if (p >= a_t1 && p < a_t)      // len == t+1: last valid step
                featsT[u * 4096 + pns[j]] = h8[j];
        }
        *(float4*)&cT[u * 4096 + scol]         = make_float4(c8[0], c8[1], c8[2], c8[3]);
        *(float4*)&cT[u * 4096 + scol + 4]     = make_float4(c8[4], c8[5], c8[6], c8[7]);
        *(float4*)&hTnext[u * 4096 + scol]     = make_float4(h8[0], h8[1], h8[2], h8[3]);
        *(float4*)&hTnext[u * 4096 + scol + 4] = make_float4(h8[4], h8[5], h8[6], h8[7]);
    }
}

// ---------------------------------------------------------------------------
// T-GEMM 128r x 128s, 8x8 micro, from pre-skewed linear W image.
// Out[r][s] = sum_k W[r][k]*X[k*xstride+s] + addm[r][s] or bias[r].
// grid (32, 8). Same conflict-free lane map / async staging as stepT.
// Phase-2: X = hTbuf (HSTRIDE, front pad = s-1 shift).
// ---------------------------------------------------------------------------
__global__ __launch_bounds__(256, 1)
void gemm_T(const float* __restrict__ WT, const float* __restrict__ X, int xstride,
            const float* __restrict__ addm, const float* __restrict__ bias,
            float* __restrict__ Out)
{
    __shared__ float w_lds[2][16 * WROW];
    __shared__ float h_lds[2][16][128];
    const int tid = threadIdx.x;
    const int tr = tid & 15;
    const int ts = tid >> 4;
    const int s0 = blockIdx.x * 128;
    const int rt = blockIdx.y;            // r0 = rt*128
    const int scol = s0 + ts * 8;
    const int wphys = tr * 8 + ((tr >> 2) << 2);

    float acc[8][8];
    #pragma unroll
    for (int x = 0; x < 8; ++x)
        #pragma unroll
        for (int y = 0; y < 8; ++y) acc[x][y] = 0.f;

    auto issue_w = [&](int c, int b) {
        const float* src = WT + (size_t)(rt * 256 + c * 16) * WROW;
        #pragma unroll
        for (int p = 0; p < 2; ++p) {
            int idx = tid + p * 256;
            gload_lds16(src + idx * 4, &w_lds[b][idx * 4]);
        }
        if (tid < 48) {
            int idx = 512 + tid;
            gload_lds16(src + idx * 4, &w_lds[b][idx * 4]);
        }
    };
    auto issue_h = [&](int k0, int b) {
        #pragma unroll
        for (int p = 0; p < 2; ++p) {
            int idx = tid + p * 256;
            int jj = idx >> 5, s4 = idx & 31;
            gload_lds16(&X[(k0 + jj) * xstride + s0 + s4 * 4],
                        &h_lds[b][jj][s4 * 4]);
        }
    };

    issue_w(0, 0); issue_h(0, 0); __syncthreads();
    for (int c = 0; c < 16; ++c) {
        const int b = c & 1;
        if (c < 15) { issue_w(c + 1, b ^ 1); issue_h((c + 1) * 16, b ^ 1); }
        #pragma unroll
        for (int k = 0; k < 16; ++k) {
            float4 w0 = *(const float4*)&w_lds[b][k * WROW + wphys];
            float4 w1 = *(const float4*)&w_lds[b][k * WROW + wphys + 4];
            float4 h0 = *(const float4*)&h_lds[b][k][ts * 8];
            float4 h1 = *(const float4*)&h_lds[b][k][ts * 8 + 4];
            float wa[8] = {w0.x, w0.y, w0.z, w0.w, w1.x, w1.y, w1.z, w1.w};
            float ha[8] = {h0.x, h0.y, h0.z, h0.w, h1.x, h1.y, h1.z, h1.w};
            #pragma unroll
            for (int ri = 0; ri < 8; ++ri)
                #pragma unroll
                for (int si = 0; si < 8; ++si)
                    acc[ri][si] += wa[ri] * ha[si];
        }
        __syncthreads();
    }

    #pragma unroll
    for (int ri = 0; ri < 8; ++ri) {
        const int r = rt * 128 + tr * 8 + ri;
        float4 z0, z1;
        if (addm) {
            float4 g0 = *(const float4*)&addm[r * 4096 + scol];
            float4 g1 = *(const float4*)&addm[r * 4096 + scol + 4];
            z0.x = acc[ri][0] + g0.x; z0.y = acc[ri][1] + g0.y;
            z0.z = acc[ri][2] + g0.z; z0.w = acc[ri][3] + g0.w;
            z1.x = acc[ri][4] + g1.x; z1.y = acc[ri][5] + g1.y;
            z1.z = acc[ri][6] + g1.z; z1.w = acc[ri][7] + g1.w;
        } else {
            float bb = bias[r];
            z0.x = acc[ri][0] + bb; z0.y = acc[ri][1] + bb;
            z0.z = acc[ri][2] + bb; z0.w = acc[ri][3] + bb;
            z1.x = acc[ri][4] + bb; z1.y = acc[ri][5] + bb;
            z1.z = acc[ri][6] + bb; z1.w = acc[ri][7] + bb;
        }
        *(float4*)&Out[r * 4096 + scol]     = z0;
        *(float4*)&Out[r * 4096 + scol + 4] = z1;
    }
}

// ---------------------------------------------------------------------------
// Sweep scan: exact per-unit affine scan of c given gate preactivations ZT,
// then h = sig(o)*tanh(c) -> hTbuf[u][1+s]. grid 256, block 256.
// ---------------------------------------------------------------------------
__global__ __launch_bounds__(256, 1)
void scan_sweep(const float* __restrict__ ZT, float* __restrict__ hTbuf)
{
    const int u = blockIdx.x;
    const int t = threadIdx.x;
    const int s0 = t * 16;

    const float* zi = ZT + (0 * 256 + u) * 4096 + s0;
    const float* zf = ZT + (1 * 256 + u) * 4096 + s0;
    const float* zg = ZT + (2 * 256 + u) * 4096 + s0;
    const float* zo = ZT + (3 * 256 + u) * 4096 + s0;

    float4 iv[4], fv[4], gv[4], ov[4];
    #pragma unroll
    for (int p = 0; p < 4; ++p) {
        iv[p] = *(const float4*)&zi[p * 4];
        fv[p] = *(const float4*)&zf[p * 4];
        gv[p] = *(const float4*)&zg[p * 4];
        ov[p] = *(const float4*)&zo[p * 4];
    }
    float af[16], uu[16];
    const float* ivp = (const float*)iv;
    const float* fvp = (const float*)fv;
    const float* gvp = (const float*)gv;
    float A = 1.f, U = 0.f;
    #pragma unroll
    for (int k = 0; k < 16; ++k) {
        af[k] = sig_(fvp[k]);
        uu[k] = sig_(ivp[k]) * th_(gvp[k]);
        U = af[k] * U + uu[k];
        A = af[k] * A;
    }

    __shared__ float As[256], Us[256];
    As[t] = A; Us[t] = U;
    __syncthreads();
    #pragma unroll
    for (int off = 1; off < 256; off <<= 1) {
        float eA = 1.f, eU = 0.f;
        if (t >= off) { eA = As[t - off]; eU = Us[t - off]; }
        __syncthreads();
        U = A * eU + U;
        A = A * eA;
        As[t] = A; Us[t] = U;
        __syncthreads();
    }
    float c = (t > 0) ? Us[t - 1] : 0.f;  // exclusive prefix -> entry c

    float* hp = hTbuf + u * HSTRIDE + 1 + s0;
    const float* ovp = (const float*)ov;
    #pragma unroll
    for (int k = 0; k < 16; ++k) {
        c = af[k] * c + uu[k];
        hp[k] = sig_(ovp[k]) * th_(c);
    }
}

// ---------------------------------------------------------------------------
// Final linear: out = h[4095] . lin_W + lin_b
// ---------------------------------------------------------------------------
__global__ __launch_bounds__(256)
void out_kernel(const float* __restrict__ hTbuf, const float* __restrict__ linW,
                const float* __restrict__ linb, float* __restrict__ out)
{
    const int tid = threadIdx.x;
    __shared__ float red_lds[4];
    float p = hTbuf[tid * HSTRIDE + 4096] * linW[tid];
    #pragma unroll
    for (int off = 1; off < 64; off <<= 1) p += __shfl_xor(p, off);
    if ((tid & 63) == 0) red_lds[tid >> 6] = p;
    __syncthreads();
    if (tid == 0)
        out[0] = red_lds[0] + red_lds[1] + red_lds[2] + red_lds[3] + linb[0];
}

extern "C" void kernel_launch(void* const* d_in, const int* in_sizes, int n_in,
                              void* d_out, int out_size, void* d_ws, size_t ws_size,
                              hipStream_t stream)
{
    const int*   tok  = (const int*)d_in[0];
    const int*   len  = (const int*)d_in[1];
    const float* emb  = (const float*)d_in[2];
    const float* tWih = (const float*)d_in[3];
    const float* tWhh = (const float*)d_in[4];
    const float* tb   = (const float*)d_in[5];
    const float* iWih = (const float*)d_in[6];
    const float* iWhh = (const float*)d_in[7];
    const float* ib   = (const float*)d_in[8];
    const float* lW   = (const float*)d_in[9];
    const float* lb   = (const float*)d_in[10];
    float* out = (float*)d_out;

    // workspace (floats), ~48 MB; ZT (phase 2) aliases hT0..featsT (dead)
    float* emb2   = (float*)d_ws;           // [2000][1024]   8 MB
    float* hT0    = emb2   + 2048000;       // [256][4096]    4 MB
    float* hT1    = hT0    + 1048576;       // [256][4096]
    float* cT     = hT1    + 1048576;       // [256][4096]
    float* featsT = cT     + 1048576;       // [256][4096]
    float* gBT    = featsT + 1048576;       // [1024][4096]  16 MB
    float* hTbuf  = gBT    + 4194304;       // [256][HSTRIDE], col0 = 0 pad
    float* tWhhT  = hTbuf  + 256 * HSTRIDE; // skewed W images, 1.1 MB each
    float* iWhhT  = tWhhT  + WTSZ;
    float* iWihT  = iWhhT  + WTSZ;
    int*   perm   = (int*)(iWihT + WTSZ);   // [4096]
    int*   actcnt = perm + 4096;            // [17]
    float* ZT     = hT0;                    // [1024][4096] alias (phase 2 only)

    // hTbuf col 0 must be 0 (h[-1])
    hipMemsetAsync(hTbuf, 0, (size_t)256 * HSTRIDE * sizeof(float), stream);

    // one-time pre-transposed + pre-skewed W images
    wtrans<<<dim3(8, 8), 256, 0, stream>>>(tWhh, tWhhT, 1);   // gate-interleaved
    wtrans<<<dim3(8, 8), 256, 0, stream>>>(iWhh, iWhhT, 0);   // linear
    wtrans<<<dim3(8, 8), 256, 0, stream>>>(iWih, iWihT, 0);   // linear

    // ---- phase 1: token LSTM, transposed, length-sorted batch-parallel ----
    sortlen<<<1, 256, 0, stream>>>(len, perm, actcnt);
    gemm_emb2<<<dim3(32, 16), 256, 0, stream>>>(emb, tWih, tb, emb2, 2000);
    step0T<<<dim3(64, 16), 256, 0, stream>>>(tok, perm, actcnt, emb2, cT, hT0,
                                             featsT);
    for (int t = 1; t < 16; ++t) {
        float* hprev = (t & 1) ? hT0 : hT1;
        float* hcur  = (t & 1) ? hT1 : hT0;
        stepT<<<dim3(32, 8), 256, 0, stream>>>(tWhhT, hprev, tok, t, emb2, perm,
                                               actcnt, cT, hcur, featsT);
    }
    // gBT[r][s] = ins_W_ih . featsT + ins_b
    gemm_T<<<dim3(32, 8), 256, 0, stream>>>(iWihT, featsT, 4096, nullptr, ib, gBT);

    // ---- phase 2: fixed-point sweeps (no cross-block sync) ----
    scan_sweep<<<256, 256, 0, stream>>>(gBT, hTbuf);    // sweep 1: h_old = 0
    for (int k = 1; k < SWEEPS; ++k) {
        gemm_T<<<dim3(32, 8), 256, 0, stream>>>(iWhhT, hTbuf, HSTRIDE, gBT,
                                                nullptr, ZT);
        scan_sweep<<<256, 256, 0, stream>>>(ZT, hTbuf);
    }

    out_kernel<<<1, 256, 0, stream>>>(hTbuf, lW, lb, out);
}